// Round 18
// baseline (697.068 us; speedup 1.0000x reference)
//
#include <hip/hip_runtime.h>

#define B_SZ 1024
#define T_SZ 128
#define HID 512
#define LAB 100

// ---- d_ws layout (byte offsets) ----
#define OFF_XC    0u          // uchar2 t-major [128][1024][2] = 256 KB
#define OFF_WH    262144u     // ushort[262144] bf16 Wh        = 512 KB
#define OFF_FC2   786432u     // ushort[51200]  bf16 fc2
#define OFF_FC2B  888832u     // float[100] (+pad)
#define OFF_WEFFT 889344u     // float[128][512] Weff^T        = 256 KB
#define OFF_BEFF  1151488u    // float[512]
#define OFF_ELEN  1153536u    // ushort[256][512] bf16 N-PERMUTED = 256 KB
#define OFF_EIPD  1415680u    // ushort[256][512] bf16 N-PERMUTED = 256 KB
#define OFF_WHP   1677824u    // ushort[65536] Wh kt12..15, frag-permuted = 128 KB
#define WS_NEED   1808896u

typedef __attribute__((ext_vector_type(8))) short short8;
typedef __attribute__((ext_vector_type(8))) unsigned short us8;
typedef __attribute__((ext_vector_type(4))) float float4v;
typedef __attribute__((ext_vector_type(4))) unsigned short us4;
typedef __attribute__((ext_vector_type(8))) __bf16 bf8_t;
typedef unsigned long long ull;

__device__ __attribute__((aligned(16))) unsigned char g_blob[WS_NEED]; // fallback only

__device__ __forceinline__ float bf2f(unsigned short u) {
    union { unsigned int i; float f; } z; z.i = ((unsigned int)u) << 16; return z.f;
}
__device__ __forceinline__ unsigned short f2bf(float f) {
    union { float f; unsigned int i; } z; z.f = f;
    unsigned int r = z.i + 0x7FFFu + ((z.i >> 16) & 1u);
    return (unsigned short)(r >> 16);
}
__device__ __forceinline__ float4v mfma16(short8 a, short8 b, float4v c) {
    return __builtin_amdgcn_mfma_f32_16x16x32_bf16(
        __builtin_bit_cast(bf8_t, a), __builtin_bit_cast(bf8_t, b), c, 0, 0, 0);
}

// ---------------------------------------------------------------------------
// K1 (66 blocks x 256): work that must precede the table build (r11-proven).
// ---------------------------------------------------------------------------
__launch_bounds__(256)
__global__ void k1_kernel(const float* __restrict__ fc1_f, const float* __restrict__ fc1b_f,
                          const float* __restrict__ x2h_f, const float* __restrict__ x2hb_f,
                          const float* __restrict__ h2hb_f,
                          float* __restrict__ wefft, float* __restrict__ beff) {
    const int tid = threadIdx.x;
    if (blockIdx.x < 64) {
        int gid = blockIdx.x * 256 + tid;     // 0..16383
        int n  = gid >> 5;                    // 0..511 (32 threads per n)
        int k0 = (gid & 31) * 4;              // 0,4,...,124
        const float* xr = x2h_f + n * 128;
        float a0 = 0.f, a1 = 0.f, a2 = 0.f, a3 = 0.f;
#pragma unroll 4
        for (int j = 0; j < 128; j++) {
            float xv = xr[j];                             // broadcast in wave
            float4v fv = *(const float4v*)(fc1_f + j * 128 + k0);  // coalesced
            a0 += xv * fv[0]; a1 += xv * fv[1];
            a2 += xv * fv[2]; a3 += xv * fv[3];
        }
        wefft[(k0 + 0) * 512 + n] = a0;       // one-time scattered stores
        wefft[(k0 + 1) * 512 + n] = a1;
        wefft[(k0 + 2) * 512 + n] = a2;
        wefft[(k0 + 3) * 512 + n] = a3;
        return;
    }
    int tg = (blockIdx.x - 64) * 256 + tid;   // 0..511
    float s = x2hb_f[tg] + h2hb_f[tg];
    const float4v* xr = (const float4v*)(x2h_f + tg * 128);
    const float4v* bb = (const float4v*)fc1b_f;
    for (int j = 0; j < 32; j++) {
        float4v a = xr[j], b = bb[j];
        s += a[0] * b[0] + a[1] * b[1] + a[2] * b[2] + a[3] * b[3];
    }
    beff[tg] = s;
}

// ---------------------------------------------------------------------------
// K2 (851 blocks x 256): table build + elementwise prep.
//  [0,256)   TABLE: bf16 tables, N-PERMUTED store (r13-verified bijection)
//  [256,512) XC:    x -> uchar2 t-major
//  [512,819) CONV:  Wh/fc2 f32->bf16 as quads; fc2b copy
//  [819,851) WHP:   Wh kt12..15 -> frag-permuted global buffer. Frag
//            (wv,nt,j,ln) stored at [((wv*4+nt)*4+j)*64+ln]*8 so the rnn's
//            fragment load is one fully-coalesced dwordx4 (16 lines/wave).
//            Values = f2bf(h2h_f[...]) — bit-identical to the old sA path.
// ---------------------------------------------------------------------------
__launch_bounds__(256)
__global__ void k2_kernel(const float* __restrict__ wefft, const float* __restrict__ beff,
                          const float* __restrict__ len_f, const float* __restrict__ ipd_f,
                          const int* __restrict__ xi, unsigned char* __restrict__ xc,
                          const float* __restrict__ h2h_f, const float* __restrict__ fc2_f,
                          const float* __restrict__ fc2b_f,
                          unsigned short* __restrict__ elen, unsigned short* __restrict__ eipd,
                          unsigned short* __restrict__ o_wh, unsigned short* __restrict__ o_fc2,
                          float* __restrict__ o_fc2b,
                          unsigned short* __restrict__ o_whp) {
    const int tid = threadIdx.x;
    if (blockIdx.x < 256) {
        int grp = blockIdx.x * 256 + tid;      // 0..65535
        int tab = grp >> 15;                   // 0: len, 1: ipd
        int g2  = grp & 32767;
        int v   = g2 >> 7;
        int nq  = (g2 & 127) * 4;              // logical n base (4 consecutive)
        const float* emb = (tab ? ipd_f : len_f) + v * 64;
        const float* wt  = wefft + tab * 64 * 512 + nq;
        float a0 = 0.f, a1 = 0.f, a2 = 0.f, a3 = 0.f;
#pragma unroll 8
        for (int k = 0; k < 64; k++) {
            float e = emb[k];
            float4v w = *(const float4v*)(wt + k * 512);
            a0 += e * w[0]; a1 += e * w[1]; a2 += e * w[2]; a3 += e * w[3];
        }
        if (tab) {
            float4v b4 = *(const float4v*)&beff[nq];
            a0 += b4[0]; a1 += b4[1]; a2 += b4[2]; a3 += b4[3];
        }
        // permuted store (r13/r14 HW-verified bijection)
        int nt = (nq >> 4) & 3, qq = (nq >> 2) & 3;
        int p0 = (nq & ~63) + ((nt >> 1) << 5) + qq * 8 + ((nt & 1) << 2);
        us4 o = { f2bf(a0), f2bf(a1), f2bf(a2), f2bf(a3) };
        unsigned short* dst = tab ? eipd : elen;
        *(us4*)&dst[v * 512 + p0] = o;
        return;
    }
    if (blockIdx.x < 512) {
        __shared__ int is64;
        if (tid == 0) {
            int nz = 0;
            for (int j = 1; j < 64; j += 2) nz |= xi[j];
            is64 = (nz == 0) ? 1 : 0;
        }
        __syncthreads();
        const int n = B_SZ * T_SZ * 2;
        const int i64 = is64;
        for (int i = (blockIdx.x - 256) * 256 + tid; i < n; i += 256 * 256) {
            int v = i64 ? xi[2 * i] : xi[i];
            v = v < 0 ? 0 : (v > 255 ? 255 : v);
            int b = i >> 8, r = i & 255, t = r >> 1, c = r & 1;
            xc[t * 2048 + b * 2 + c] = (unsigned char)v;
        }
        return;
    }
    if (blockIdx.x < 819) {
        // ---- CONV role, vectorized: 78336 quads + 100 scalars ----
        const int NW4 = 65536;    // Wh quads (262144/4)
        const int NF4 = 12800;    // fc2 quads (51200/4)
        int gid = (blockIdx.x - 512) * 256 + tid;
        if (gid < NW4) {
            float4v a = *(const float4v*)(h2h_f + gid * 4);
            us4 o = { f2bf(a[0]), f2bf(a[1]), f2bf(a[2]), f2bf(a[3]) };
            *(us4*)&o_wh[gid * 4] = o;
        } else if (gid < NW4 + NF4) {
            int j = gid - NW4;
            float4v a = *(const float4v*)(fc2_f + j * 4);
            us4 o = { f2bf(a[0]), f2bf(a[1]), f2bf(a[2]), f2bf(a[3]) };
            *(us4*)&o_fc2[j * 4] = o;
        } else if (gid < NW4 + NF4 + 100) {
            int j = gid - NW4 - NF4;
            o_fc2b[j] = fc2b_f[j];
        }
        return;
    }
    // ---- WHP role: 8192 frags, one per thread ----
    {
        int gid = (blockIdx.x - 819) * 256 + tid;   // 0..8191
        int lnw = gid & 63;
        int j   = (gid >> 6) & 3;
        int nt  = (gid >> 8) & 3;
        int wvp = gid >> 10;                        // 0..7
        int mcolp = lnw & 15, qp = lnw >> 4;
        const float* s = h2h_f + (wvp * 64 + nt * 16 + mcolp) * 512 + (12 + j) * 32 + qp * 8;
        float4v a = *(const float4v*)s;
        float4v d = *(const float4v*)(s + 4);
        us8 o = { f2bf(a[0]), f2bf(a[1]), f2bf(a[2]), f2bf(a[3]),
                  f2bf(d[0]), f2bf(d[1]), f2bf(d[2]), f2bf(d[3]) };
        *(us8*)&o_whp[gid * 8] = o;
    }
}

// ---------------------------------------------------------------------------
// RNN v10: r14 structure with Wh kt12..15 moved OFF the LDS pipe onto L2:
// fragments read from the frag-permuted global buffer whp (one coalesced
// dwordx4 per frag, 16 lines/wave) via a 2-stage pipeline — j=0 frags issued
// at step top (land under the ~600-cyc kt0..11 AGPR phase), j+1 issued during
// j's MFMAs. LDS reads/step/CU: 256 KB -> 128 KB (bh only). LDS = 32 KB
// (h dbuf only). Values bit-identical -> absmax must stay 0.001953125.
// Tripwire: WRITE_SIZE must stay 784 KB (fnx/fcur = 32 transient VGPRs;
// peak live ~80 of 128). Everything else identical to r14's proven kernel.
// ---------------------------------------------------------------------------
__launch_bounds__(512, 2)
__global__ void rnn_kernel(const unsigned short* __restrict__ w_wh,
                           const unsigned short* __restrict__ w_whp,
                           const unsigned char* __restrict__ w_xc,
                           const unsigned short* __restrict__ w_elen,
                           const unsigned short* __restrict__ w_eipd,
                           const unsigned short* __restrict__ w_fc2,
                           const float* __restrict__ w_fc2b,
                           float* __restrict__ out) {
    extern __shared__ unsigned short sm2[];
    unsigned short* sH = sm2;            // h dbuf: 2 x 8192 ushorts (32 KB)

    const int tid  = threadIdx.x;
    const int wv   = tid >> 6;           // 0..7
    const int ln   = tid & 63;
    const int mcol = ln & 15;            // batch col within block
    const int q    = ln >> 4;
    const int g    = blockIdx.x;
    const int b0   = g * 16;
    const int n0   = wv * 64;            // wave owns hidden rows n0..n0+63

    // ---- zero h buffer 0 ----
    {
        uint4 z = {0, 0, 0, 0};
        *(uint4*)&sH[tid * 8] = z;
        *(uint4*)&sH[(512 + tid) * 8] = z;
    }
    // ---- Wh kt 0..11 into registers: 48 frags = 192 regs (AGPR) ----
    short8 whr[4][12];
#pragma unroll
    for (int nt = 0; nt < 4; nt++)
#pragma unroll
        for (int kt = 0; kt < 12; kt++)
            whr[nt][kt] = *(const short8*)(w_wh + (n0 + nt * 16 + mcol) * 512 + kt * 32 + q * 8);

    // ---- strength-reduced swizzle offsets (ushort units) ----
    const int qlo = (q ^ (mcol & 3)) * 8;
    int ej[4];
#pragma unroll
    for (int j = 0; j < 4; j++)
        ej[j] = ((j * 4) ^ (mcol & 12)) * 8;
    const int base_b = mcol * 512 + qlo;          // h-read base
    int hw_off[4];
#pragma unroll
    for (int nt = 0; nt < 4; nt++) {
        int n = n0 + nt * 16 + q * 4;
        hw_off[nt] = mcol * 512 + (((n >> 3) ^ mcol) & 63) * 8 + (n & 7);
    }
    // ---- whp fragment base: frag(nt,j) at whp_t + nt*2048 + j*512 ----
    const unsigned short* whp_t = w_whp + wv * 8192 + ln * 8;

    // ---- gather pipeline prologue (permuted bf16 tables, uchar2 idx) ----
    const int xb2  = (b0 + mcol) * 2;     // byte offset within a t-slice
    const int ecol = n0 + q * 8;          // permuted window offset
    us8 tL0, tL1, tI0, tI1;
    {
        unsigned int i0 = *(const unsigned short*)&w_xc[xb2];          // x[t=0]
        const unsigned short* eL = w_elen + (i0 & 255u) * 512 + ecol;
        const unsigned short* eI = w_eipd + (i0 >> 8) * 512 + ecol;
        tL0 = *(const us8*)eL;  tL1 = *(const us8*)(eL + 32);
        tI0 = *(const us8*)eI;  tI1 = *(const us8*)(eI + 32);
    }
    unsigned int idxP = *(const unsigned short*)&w_xc[2048 + xb2];     // x[t=1]

    __syncthreads();

    for (int t = 0; t < T_SZ; t++) {
        const unsigned short* hRd = sH + ((t & 1) << 13);
        unsigned short* hWr = sH + (((t + 1) & 1) << 13);

        // ---- acc init: unpack permuted us8 pairs (loads from t-1, landed) --
        float4v acc[4];
#pragma unroll
        for (int r = 0; r < 4; r++) {
            acc[0][r] = bf2f(tL0[r])     + bf2f(tI0[r]);
            acc[1][r] = bf2f(tL0[4 + r]) + bf2f(tI0[4 + r]);
            acc[2][r] = bf2f(tL1[r])     + bf2f(tI1[r]);
            acc[3][r] = bf2f(tL1[4 + r]) + bf2f(tI1[4 + r]);
        }
        // ---- issue next-step table loads (idxP resident -> no chain) ----
        if (t + 1 < T_SZ) {
            const unsigned short* eL = w_elen + (idxP & 255u) * 512 + ecol;
            const unsigned short* eI = w_eipd + (idxP >> 8) * 512 + ecol;
            tL0 = *(const us8*)eL;  tL1 = *(const us8*)(eL + 32);
            tI0 = *(const us8*)eI;  tI1 = *(const us8*)(eI + 32);
            if (t + 2 < T_SZ)
                idxP = *(const unsigned short*)&w_xc[(t + 2) * 2048 + xb2];
        }
        // ---- issue j=0 Wh-fragment loads (land under the AGPR phase) ----
        us8 fnx[4];
#pragma unroll
        for (int nt = 0; nt < 4; nt++)
            fnx[nt] = *(const us8*)(whp_t + nt * 2048);

        // ---- Wh MFMAs: kt 0..11 from regs ----
#pragma unroll
        for (int kt = 0; kt < 12; kt++) {
            short8 bh = *(const short8*)&hRd[base_b + ej[kt & 3] + (kt >> 2) * 128];
#pragma unroll
            for (int nt = 0; nt < 4; nt++)
                acc[nt] = mfma16(whr[nt][kt], bh, acc[nt]);
        }
        // ---- kt 12..15: Wh frags from L2 (2-stage pipeline), bh from LDS ---
#pragma unroll
        for (int j = 0; j < 4; j++) {
            us8 fcur[4];
#pragma unroll
            for (int nt = 0; nt < 4; nt++) fcur[nt] = fnx[nt];
            if (j < 3) {
#pragma unroll
                for (int nt = 0; nt < 4; nt++)
                    fnx[nt] = *(const us8*)(whp_t + nt * 2048 + (j + 1) * 512);
            }
            short8 bh = *(const short8*)&hRd[base_b + ej[j] + 384];
#pragma unroll
            for (int nt = 0; nt < 4; nt++)
                acc[nt] = mfma16(__builtin_bit_cast(short8, fcur[nt]), bh, acc[nt]);
        }

        // ---- fast tanh -> bf16, write h(t+1) into other buffer ----
#pragma unroll
        for (int nt = 0; nt < 4; nt++) {
            unsigned short o[4];
#pragma unroll
            for (int r = 0; r < 4; r++) {
                float e  = __expf(2.0f * acc[nt][r]);
                float th = 1.0f - 2.0f * __builtin_amdgcn_rcpf(e + 1.0f);
                o[r] = f2bf(th);
            }
            us4 v4 = { o[0], o[1], o[2], o[3] };
            *(us4*)&hWr[hw_off[nt]] = v4;
        }
        __syncthreads();   // h(t+1) visible to all waves before next step
    }

    // final h is in buffer 0 (T_SZ even)
    unsigned short* hF = sH;

    // ---- fc2 epilogue: waves 0..6 cover 112 >= 100 labels ----
    if (wv < 7) {
        int lA = wv * 16 + mcol; if (lA > 99) lA = 99;
        float4v a2 = {0.f, 0.f, 0.f, 0.f};
#pragma unroll
        for (int kt = 0; kt < 16; kt++) {
            short8 fa = *(const short8*)(w_fc2 + lA * 512 + kt * 32 + q * 8);
            short8 bh = *(const short8*)&hF[base_b + ej[kt & 3] + (kt >> 2) * 128];
            a2 = mfma16(fa, bh, a2);
        }
#pragma unroll
        for (int r = 0; r < 4; r++) {
            int l = wv * 16 + q * 4 + r;
            if (l < 100) out[(b0 + mcol) * 100 + l] = a2[r] + w_fc2b[l];
        }
    }
}

extern "C" void kernel_launch(void* const* d_in, const int* in_sizes, int n_in,
                              void* d_out, int out_size, void* d_ws, size_t ws_size,
                              hipStream_t stream) {
    unsigned char* base = (unsigned char*)d_ws;
    if (ws_size < (size_t)WS_NEED) {
        void* p = nullptr;
        hipGetSymbolAddress(&p, HIP_SYMBOL(g_blob));
        base = (unsigned char*)p;
    }
    unsigned char*  w_xc    = base + OFF_XC;
    unsigned short* w_wh    = (unsigned short*)(base + OFF_WH);
    unsigned short* w_fc2   = (unsigned short*)(base + OFF_FC2);
    float*          w_fc2b  = (float*)(base + OFF_FC2B);
    float*          w_wefft = (float*)(base + OFF_WEFFT);
    float*          w_beff  = (float*)(base + OFF_BEFF);
    unsigned short* w_elen  = (unsigned short*)(base + OFF_ELEN);
    unsigned short* w_eipd  = (unsigned short*)(base + OFF_EIPD);
    unsigned short* w_whp   = (unsigned short*)(base + OFF_WHP);

    static bool attr_set = false;
    if (!attr_set) {
        hipFuncSetAttribute((const void*)rnn_kernel,
                            hipFuncAttributeMaxDynamicSharedMemorySize, 32768);
        attr_set = true;
    }

    k1_kernel<<<66, 256, 0, stream>>>(
        (const float*)d_in[3], (const float*)d_in[4],
        (const float*)d_in[5], (const float*)d_in[6], (const float*)d_in[8],
        w_wefft, w_beff);
    k2_kernel<<<851, 256, 0, stream>>>(
        w_wefft, w_beff,
        (const float*)d_in[1], (const float*)d_in[2],
        (const int*)d_in[0], w_xc,
        (const float*)d_in[7], (const float*)d_in[9], (const float*)d_in[10],
        w_elen, w_eipd, w_wh, w_fc2, w_fc2b, w_whp);
    rnn_kernel<<<64, 512, 32768, stream>>>(
        w_wh, w_whp, w_xc, w_elen, w_eipd, w_fc2, w_fc2b, (float*)d_out);
}

// Round 19
// 355.730 us; speedup vs baseline: 1.9595x; 1.9595x over previous
//
#include <hip/hip_runtime.h>

#define B_SZ 1024
#define T_SZ 128
#define HID 512
#define LAB 100

// ---- d_ws layout (byte offsets) ----
#define OFF_XC    0u          // uchar2 t-major [128][1024][2] = 256 KB
#define OFF_WH    262144u     // ushort[262144] bf16 Wh        = 512 KB
#define OFF_FC2   786432u     // ushort[51200]  bf16 fc2
#define OFF_FC2B  888832u     // float[100] (+pad)
#define OFF_WEFFT 889344u     // float[128][512] Weff^T        = 256 KB
#define OFF_BEFF  1151488u    // float[512]
#define OFF_ELEN  1153536u    // ushort[256][512] bf16 N-PERMUTED = 256 KB
#define OFF_EIPD  1415680u    // ushort[256][512] bf16 N-PERMUTED = 256 KB
#define WS_NEED   1677824u

typedef __attribute__((ext_vector_type(8))) short short8;
typedef __attribute__((ext_vector_type(8))) unsigned short us8;
typedef __attribute__((ext_vector_type(4))) float float4v;
typedef __attribute__((ext_vector_type(4))) unsigned short us4;
typedef __attribute__((ext_vector_type(8))) __bf16 bf8_t;
typedef unsigned long long ull;

__device__ __attribute__((aligned(16))) unsigned char g_blob[WS_NEED]; // fallback only

__device__ __forceinline__ float bf2f(unsigned short u) {
    union { unsigned int i; float f; } z; z.i = ((unsigned int)u) << 16; return z.f;
}
__device__ __forceinline__ unsigned short f2bf(float f) {
    union { float f; unsigned int i; } z; z.f = f;
    unsigned int r = z.i + 0x7FFFu + ((z.i >> 16) & 1u);
    return (unsigned short)(r >> 16);
}
__device__ __forceinline__ float4v mfma16(short8 a, short8 b, float4v c) {
    return __builtin_amdgcn_mfma_f32_16x16x32_bf16(
        __builtin_bit_cast(bf8_t, a), __builtin_bit_cast(bf8_t, b), c, 0, 0, 0);
}

// ---------------------------------------------------------------------------
// K1 (66 blocks x 256): work that must precede the table build (r11-proven).
//  [0,64) : Weff^T[k][n] coalesced mapping (broadcast x2h + float4 fc1 rows)
//  [64,66): beff[n] = x2hb[n]+h2hb[n]+sum_j x2h[n][j]*fc1b[j]  (f32 exact)
// ---------------------------------------------------------------------------
__launch_bounds__(256)
__global__ void k1_kernel(const float* __restrict__ fc1_f, const float* __restrict__ fc1b_f,
                          const float* __restrict__ x2h_f, const float* __restrict__ x2hb_f,
                          const float* __restrict__ h2hb_f,
                          float* __restrict__ wefft, float* __restrict__ beff) {
    const int tid = threadIdx.x;
    if (blockIdx.x < 64) {
        int gid = blockIdx.x * 256 + tid;     // 0..16383
        int n  = gid >> 5;                    // 0..511 (32 threads per n)
        int k0 = (gid & 31) * 4;              // 0,4,...,124
        const float* xr = x2h_f + n * 128;
        float a0 = 0.f, a1 = 0.f, a2 = 0.f, a3 = 0.f;
#pragma unroll 4
        for (int j = 0; j < 128; j++) {
            float xv = xr[j];                             // broadcast in wave
            float4v fv = *(const float4v*)(fc1_f + j * 128 + k0);  // coalesced
            a0 += xv * fv[0]; a1 += xv * fv[1];
            a2 += xv * fv[2]; a3 += xv * fv[3];
        }
        wefft[(k0 + 0) * 512 + n] = a0;       // one-time scattered stores
        wefft[(k0 + 1) * 512 + n] = a1;
        wefft[(k0 + 2) * 512 + n] = a2;
        wefft[(k0 + 3) * 512 + n] = a3;
        return;
    }
    int tg = (blockIdx.x - 64) * 256 + tid;   // 0..511
    float s = x2hb_f[tg] + h2hb_f[tg];
    const float4v* xr = (const float4v*)(x2h_f + tg * 128);
    const float4v* bb = (const float4v*)fc1b_f;
    for (int j = 0; j < 32; j++) {
        float4v a = xr[j], b = bb[j];
        s += a[0] * b[0] + a[1] * b[1] + a[2] * b[2] + a[3] * b[3];
    }
    beff[tg] = s;
}

// ---------------------------------------------------------------------------
// K2 (819 blocks x 256): table build + elementwise prep (r14/r17-proven).
//  [0,256)   TABLE: bf16 tables, N-PERMUTED store (r13-verified bijection)
//  [256,512) XC:    x -> uchar2 t-major
//  [512,819) CONV:  Wh/fc2 f32->bf16 as quads; fc2b copy
// ---------------------------------------------------------------------------
__launch_bounds__(256)
__global__ void k2_kernel(const float* __restrict__ wefft, const float* __restrict__ beff,
                          const float* __restrict__ len_f, const float* __restrict__ ipd_f,
                          const int* __restrict__ xi, unsigned char* __restrict__ xc,
                          const float* __restrict__ h2h_f, const float* __restrict__ fc2_f,
                          const float* __restrict__ fc2b_f,
                          unsigned short* __restrict__ elen, unsigned short* __restrict__ eipd,
                          unsigned short* __restrict__ o_wh, unsigned short* __restrict__ o_fc2,
                          float* __restrict__ o_fc2b) {
    const int tid = threadIdx.x;
    if (blockIdx.x < 256) {
        int grp = blockIdx.x * 256 + tid;      // 0..65535
        int tab = grp >> 15;                   // 0: len, 1: ipd
        int g2  = grp & 32767;
        int v   = g2 >> 7;
        int nq  = (g2 & 127) * 4;              // logical n base (4 consecutive)
        const float* emb = (tab ? ipd_f : len_f) + v * 64;
        const float* wt  = wefft + tab * 64 * 512 + nq;
        float a0 = 0.f, a1 = 0.f, a2 = 0.f, a3 = 0.f;
#pragma unroll 8
        for (int k = 0; k < 64; k++) {
            float e = emb[k];
            float4v w = *(const float4v*)(wt + k * 512);
            a0 += e * w[0]; a1 += e * w[1]; a2 += e * w[2]; a3 += e * w[3];
        }
        if (tab) {
            float4v b4 = *(const float4v*)&beff[nq];
            a0 += b4[0]; a1 += b4[1]; a2 += b4[2]; a3 += b4[3];
        }
        // permuted store (r13/r14 HW-verified bijection)
        int nt = (nq >> 4) & 3, qq = (nq >> 2) & 3;
        int p0 = (nq & ~63) + ((nt >> 1) << 5) + qq * 8 + ((nt & 1) << 2);
        us4 o = { f2bf(a0), f2bf(a1), f2bf(a2), f2bf(a3) };
        unsigned short* dst = tab ? eipd : elen;
        *(us4*)&dst[v * 512 + p0] = o;
        return;
    }
    if (blockIdx.x < 512) {
        __shared__ int is64;
        if (tid == 0) {
            int nz = 0;
            for (int j = 1; j < 64; j += 2) nz |= xi[j];
            is64 = (nz == 0) ? 1 : 0;
        }
        __syncthreads();
        const int n = B_SZ * T_SZ * 2;
        const int i64 = is64;
        for (int i = (blockIdx.x - 256) * 256 + tid; i < n; i += 256 * 256) {
            int v = i64 ? xi[2 * i] : xi[i];
            v = v < 0 ? 0 : (v > 255 ? 255 : v);
            int b = i >> 8, r = i & 255, t = r >> 1, c = r & 1;
            xc[t * 2048 + b * 2 + c] = (unsigned char)v;
        }
        return;
    }
    // ---- CONV role, vectorized: 78336 quads + 100 scalars over 78592 thr ----
    const int NW4 = 65536;    // Wh quads (262144/4)
    const int NF4 = 12800;    // fc2 quads (51200/4)
    int gid = (blockIdx.x - 512) * 256 + tid;
    if (gid < NW4) {
        float4v a = *(const float4v*)(h2h_f + gid * 4);
        us4 o = { f2bf(a[0]), f2bf(a[1]), f2bf(a[2]), f2bf(a[3]) };
        *(us4*)&o_wh[gid * 4] = o;
    } else if (gid < NW4 + NF4) {
        int j = gid - NW4;
        float4v a = *(const float4v*)(fc2_f + j * 4);
        us4 o = { f2bf(a[0]), f2bf(a[1]), f2bf(a[2]), f2bf(a[3]) };
        *(us4*)&o_fc2[j * 4] = o;
    } else if (gid < NW4 + NF4 + 100) {
        int j = gid - NW4 - NF4;
        o_fc2b[j] = fc2b_f[j];
    }
}

// ---------------------------------------------------------------------------
// RNN v8 — TERMINAL configuration (276.5 us proven r14/r17). Compiled ALONE
// (r13/r16: co-compiling other roles degrades this loop's codegen ~30%).
// Structure: 64 blocks x 512 thr (8 waves, 2/SIMD — r3: 1/SIMD fails);
// Wh kt0..11 in 192 AGPRs — the register budget is EXACTLY full at the
// 320-reg/wave cliff (640/SIMD pool): r1/r15/r18 all spilled when adding
// any in-loop register state. kt12..15 in 128 KB swizzled LDS; h dbuf 32 KB;
// 1 barrier/step; fast tanh (rcp, no clamp); strength-reduced XOR addressing;
// bf16 N-permuted table gather as 4 x us8 (64 L1 lines/wave/step — the
// gather cost is line-transactions, not bytes); uchar2 t-major idx;
// 2-deep software pipeline (idxP one step ahead, add at consume site).
// Structural floor: LDS pipe carries 256 KB/step (bh broadcast mandatory —
// every wave needs all of h(t) for the K=512 contraction) ~3000 cyc +
// ~2100 cyc convoy latency = measured 276 us over 128 steps.
// ---------------------------------------------------------------------------
__launch_bounds__(512, 2)
__global__ void rnn_kernel(const unsigned short* __restrict__ w_wh,
                           const unsigned char* __restrict__ w_xc,
                           const unsigned short* __restrict__ w_elen,
                           const unsigned short* __restrict__ w_eipd,
                           const unsigned short* __restrict__ w_fc2,
                           const float* __restrict__ w_fc2b,
                           float* __restrict__ out) {
    extern __shared__ unsigned short sm2[];
    unsigned short* sA = sm2;            // Wh k 384..511: 65536 ushorts (128 KB)
    unsigned short* sH = sm2 + 65536;    // h dbuf: 2 x 8192 ushorts (32 KB)

    const int tid  = threadIdx.x;
    const int wv   = tid >> 6;           // 0..7
    const int ln   = tid & 63;
    const int mcol = ln & 15;            // batch col within block
    const int q    = ln >> 4;
    const int g    = blockIdx.x;
    const int b0   = g * 16;
    const int n0   = wv * 64;            // wave owns hidden rows n0..n0+63

    // ---- stage Wh kt 12..15 into LDS (swizzled) ----
    for (int it = 0; it < 16; it++) {
        int chunk = it * 512 + tid;          // 0..8191
        int r = chunk >> 4, c = chunk & 15;
        uint4 v = *(const uint4*)(w_wh + r * 512 + 384 + c * 8);
        *(uint4*)&sA[r * 128 + ((c ^ (r & 15)) & 15) * 8] = v;
    }
    // ---- zero h buffer 0 ----
    {
        uint4 z = {0, 0, 0, 0};
        *(uint4*)&sH[tid * 8] = z;
        *(uint4*)&sH[(512 + tid) * 8] = z;
    }
    // ---- Wh kt 0..11 into registers: 48 frags = 192 regs (AGPR) ----
    short8 whr[4][12];
#pragma unroll
    for (int nt = 0; nt < 4; nt++)
#pragma unroll
        for (int kt = 0; kt < 12; kt++)
            whr[nt][kt] = *(const short8*)(w_wh + (n0 + nt * 16 + mcol) * 512 + kt * 32 + q * 8);

    // ---- strength-reduced swizzle offsets (ushort units) ----
    const int qlo = (q ^ (mcol & 3)) * 8;
    int ej[4];
#pragma unroll
    for (int j = 0; j < 4; j++)
        ej[j] = ((j * 4) ^ (mcol & 12)) * 8;
    const int base_b = mcol * 512 + qlo;          // h-read base
    const int fbase  = (n0 + mcol) * 128 + qlo;   // sA-read base
    int hw_off[4];
#pragma unroll
    for (int nt = 0; nt < 4; nt++) {
        int n = n0 + nt * 16 + q * 4;
        hw_off[nt] = mcol * 512 + (((n >> 3) ^ mcol) & 63) * 8 + (n & 7);
    }

    // ---- gather pipeline prologue (permuted bf16 tables, uchar2 idx) ----
    const int xb2  = (b0 + mcol) * 2;     // byte offset within a t-slice
    const int ecol = n0 + q * 8;          // permuted window offset
    us8 tL0, tL1, tI0, tI1;
    {
        unsigned int i0 = *(const unsigned short*)&w_xc[xb2];          // x[t=0]
        const unsigned short* eL = w_elen + (i0 & 255u) * 512 + ecol;
        const unsigned short* eI = w_eipd + (i0 >> 8) * 512 + ecol;
        tL0 = *(const us8*)eL;  tL1 = *(const us8*)(eL + 32);
        tI0 = *(const us8*)eI;  tI1 = *(const us8*)(eI + 32);
    }
    unsigned int idxP = *(const unsigned short*)&w_xc[2048 + xb2];     // x[t=1]

    __syncthreads();

    for (int t = 0; t < T_SZ; t++) {
        const unsigned short* hRd = sH + ((t & 1) << 13);
        unsigned short* hWr = sH + (((t + 1) & 1) << 13);

        // ---- acc init: unpack permuted us8 pairs (loads from t-1, landed) --
        float4v acc[4];
#pragma unroll
        for (int r = 0; r < 4; r++) {
            acc[0][r] = bf2f(tL0[r])     + bf2f(tI0[r]);
            acc[1][r] = bf2f(tL0[4 + r]) + bf2f(tI0[4 + r]);
            acc[2][r] = bf2f(tL1[r])     + bf2f(tI1[r]);
            acc[3][r] = bf2f(tL1[4 + r]) + bf2f(tI1[4 + r]);
        }
        // ---- issue next-step table loads (idxP resident -> no chain) ----
        if (t + 1 < T_SZ) {
            const unsigned short* eL = w_elen + (idxP & 255u) * 512 + ecol;
            const unsigned short* eI = w_eipd + (idxP >> 8) * 512 + ecol;
            tL0 = *(const us8*)eL;  tL1 = *(const us8*)(eL + 32);
            tI0 = *(const us8*)eI;  tI1 = *(const us8*)(eI + 32);
            if (t + 2 < T_SZ)
                idxP = *(const unsigned short*)&w_xc[(t + 2) * 2048 + xb2];
        }

        // ---- Wh MFMAs: kt 0..11 from regs ----
#pragma unroll
        for (int kt = 0; kt < 12; kt++) {
            short8 bh = *(const short8*)&hRd[base_b + ej[kt & 3] + (kt >> 2) * 128];
#pragma unroll
            for (int nt = 0; nt < 4; nt++)
                acc[nt] = mfma16(whr[nt][kt], bh, acc[nt]);
        }
        // ---- kt 12..15 from LDS ----
#pragma unroll
        for (int j = 0; j < 4; j++) {
            short8 bh = *(const short8*)&hRd[base_b + ej[j] + 384];
#pragma unroll
            for (int nt = 0; nt < 4; nt++) {
                short8 fa = *(const short8*)&sA[fbase + nt * 2048 + ej[j]];
                acc[nt] = mfma16(fa, bh, acc[nt]);
            }
        }

        // ---- fast tanh -> bf16, write h(t+1) into other buffer ----
#pragma unroll
        for (int nt = 0; nt < 4; nt++) {
            unsigned short o[4];
#pragma unroll
            for (int r = 0; r < 4; r++) {
                float e  = __expf(2.0f * acc[nt][r]);
                float th = 1.0f - 2.0f * __builtin_amdgcn_rcpf(e + 1.0f);
                o[r] = f2bf(th);
            }
            us4 v4 = { o[0], o[1], o[2], o[3] };
            *(us4*)&hWr[hw_off[nt]] = v4;
        }
        __syncthreads();   // h(t+1) visible to all waves before next step
    }

    // final h is in buffer 0 (T_SZ even)
    unsigned short* hF = sH;

    // ---- fc2 epilogue: waves 0..6 cover 112 >= 100 labels ----
    if (wv < 7) {
        int lA = wv * 16 + mcol; if (lA > 99) lA = 99;
        float4v a2 = {0.f, 0.f, 0.f, 0.f};
#pragma unroll
        for (int kt = 0; kt < 16; kt++) {
            short8 fa = *(const short8*)(w_fc2 + lA * 512 + kt * 32 + q * 8);
            short8 bh = *(const short8*)&hF[base_b + ej[kt & 3] + (kt >> 2) * 128];
            a2 = mfma16(fa, bh, a2);
        }
#pragma unroll
        for (int r = 0; r < 4; r++) {
            int l = wv * 16 + q * 4 + r;
            if (l < 100) out[(b0 + mcol) * 100 + l] = a2[r] + w_fc2b[l];
        }
    }
}

extern "C" void kernel_launch(void* const* d_in, const int* in_sizes, int n_in,
                              void* d_out, int out_size, void* d_ws, size_t ws_size,
                              hipStream_t stream) {
    unsigned char* base = (unsigned char*)d_ws;
    if (ws_size < (size_t)WS_NEED) {
        void* p = nullptr;
        hipGetSymbolAddress(&p, HIP_SYMBOL(g_blob));
        base = (unsigned char*)p;
    }
    unsigned char*  w_xc    = base + OFF_XC;
    unsigned short* w_wh    = (unsigned short*)(base + OFF_WH);
    unsigned short* w_fc2   = (unsigned short*)(base + OFF_FC2);
    float*          w_fc2b  = (float*)(base + OFF_FC2B);
    float*          w_wefft = (float*)(base + OFF_WEFFT);
    float*          w_beff  = (float*)(base + OFF_BEFF);
    unsigned short* w_elen  = (unsigned short*)(base + OFF_ELEN);
    unsigned short* w_eipd  = (unsigned short*)(base + OFF_EIPD);

    static bool attr_set = false;
    if (!attr_set) {
        hipFuncSetAttribute((const void*)rnn_kernel,
                            hipFuncAttributeMaxDynamicSharedMemorySize, 163840);
        attr_set = true;
    }

    k1_kernel<<<66, 256, 0, stream>>>(
        (const float*)d_in[3], (const float*)d_in[4],
        (const float*)d_in[5], (const float*)d_in[6], (const float*)d_in[8],
        w_wefft, w_beff);
    k2_kernel<<<819, 256, 0, stream>>>(
        w_wefft, w_beff,
        (const float*)d_in[1], (const float*)d_in[2],
        (const int*)d_in[0], w_xc,
        (const float*)d_in[7], (const float*)d_in[9], (const float*)d_in[10],
        w_elen, w_eipd, w_wh, w_fc2, w_fc2b);
    rnn_kernel<<<64, 512, 163840, stream>>>(
        w_wh, w_xc, w_elen, w_eipd, w_fc2, w_fc2b, (float*)d_out);
}